// Round 14
// baseline (72.624 us; speedup 1.0000x reference)
//
#include <hip/hip_runtime.h>
#include <stdint.h>

#define NB 16
#define NA 8400
#define NA_PAD 9216
#define NCH 84
#define NCLS 80
#define CANDN 2048
#define MAXDET 300

typedef unsigned long long u64;

// ---------------- workspace layout (bytes) ----------------
static const size_t OFF_SU   = 0;         // 16*8400*4  = 537600
static const size_t OFF_CLS  = 537600;    // 16*8400*4  = 537600
static const size_t OFF_BOX  = 1075200;   // 16*8400*16 = 2150400
static const size_t OFF_KEY  = 3225600;   // 16*2048*8  = 262144
static const size_t OFF_NMSB = 3487744;   // 16*2048*16 = 524288
static const size_t OFF_AREA = 4012032;   // 16*2048*4  = 131072
static const size_t OFF_H12  = 4143104;   // 16*4096*4  = 262144
// total ~4.4 MB

// ---------- kernel 0: zero the h12 histograms (256 KB) ----------
__global__ __launch_bounds__(256) void zero_kernel(int* __restrict__ h12) {
  h12[blockIdx.x * 256 + threadIdx.x] = 0;
}

// ---------- kernel 1: score/argmax + boxT + deduped 4096-bin histogram ----------
__global__ __launch_bounds__(256) void score_kernel(const float* __restrict__ pred,
                                                    unsigned* __restrict__ sug,
                                                    int* __restrict__ cls,
                                                    float4* __restrict__ boxT,
                                                    int* __restrict__ h12) {
  int a = blockIdx.x * 256 + threadIdx.x;
  int b = blockIdx.y;
  if (a >= NA) return;
  int lane = threadIdx.x & 63;
  const float* pbase = pred + (size_t)b * (NCH * NA);
  const float* p = pbase + 4 * NA + a;
  float best = p[0];
  int bc = 0;
#pragma unroll 8
  for (int c = 1; c < NCLS; ++c) {
    float v = p[(size_t)c * NA];
    if (v > best) { best = v; bc = c; }  // strict > : first-index argmax
  }
  unsigned u = ~__float_as_uint(best);  // ascending u == descending score
  sug[(size_t)b * NA + a] = u;
  cls[(size_t)b * NA + a] = bc;
  boxT[(size_t)b * NA + a] =
      make_float4(pbase[a], pbase[NA + a], pbase[2 * NA + a], pbase[3 * NA + a]);
  // wave-deduped histogram atomic (scores cluster -> same-bin storms otherwise)
  u64 m = __ballot(true);
#pragma unroll
  for (int bit = 31; bit >= 20; --bit) {
    u64 bb = __ballot((u >> bit) & 1);
    m &= ((u >> bit) & 1) ? bb : ~bb;
  }
  u64 below = (lane == 0) ? 0ULL : ((1ULL << lane) - 1ULL);
  if ((m & below) == 0ULL)
    atomicAdd(&h12[b * 4096 + (int)(u >> 20)], (int)__popcll(m));
}

__device__ inline u64 shflx64(u64 v, int m) {
  int lo = __shfl_xor((int)(unsigned)(v & 0xFFFFFFFFu), m, 64);
  int hi = __shfl_xor((int)(unsigned)(v >> 32), m, 64);
  return (((u64)(unsigned)hi) << 32) | (unsigned)lo;
}

__device__ inline u64 cswap(u64 a, u64 b, int s, int j, int kk) {
  bool low = (s & j) == 0;
  bool asc = (s & kk) == 0;
  bool takeMin = (low == asc);
  u64 mn = (a < b) ? a : b;
  u64 mx = (a < b) ? b : a;
  return takeMin ? mn : mx;
}

// exact division-free IoU>0.45f compare (25x24-bit f64 product is exact)
__device__ inline bool iou_gt(float4 bi, float ai, float4 bj, float aj) {
  const double THR = 0x1.CCCCCC8p-2;  // 0.45f + 2^-26 exactly
  float ix1 = fmaxf(bi.x, bj.x);
  float iy1 = fmaxf(bi.y, bj.y);
  float ix2 = fminf(bi.z, bj.z);
  float iy2 = fminf(bi.w, bj.w);
  float iw = fmaxf(__fsub_rn(ix2, ix1), 0.0f);
  float ih = fmaxf(__fsub_rn(iy2, iy1), 0.0f);
  float inter = __fmul_rn(iw, ih);
  float den = __fadd_rn(__fsub_rn(__fadd_rn(ai, aj), inter), 1e-7f);
  return (double)inter > THR * (double)den;
}

// ---------- kernel 2: h12-guided select, two sparse passes ----------
__global__ __launch_bounds__(1024) void select_kernel(const unsigned* __restrict__ sug,
                                                      const int* __restrict__ h12g,
                                                      u64* __restrict__ keybuf) {
  __shared__ alignas(16) unsigned su[NA];  // 33600 B
  __shared__ int histL[4096];              // 16384 B (pass A uses first 256)
  __shared__ int cum[256];
  __shared__ int tielist[1024];
  __shared__ int wtot[16];
  __shared__ unsigned sh_pref;
  __shared__ int sh_k, sh_g, sh_cnt;

  int b = blockIdx.x;
  int tid = threadIdx.x;
  int lane = tid & 63;
  int wv = tid >> 6;

  if (tid == 0) { sh_pref = 0; sh_k = CANDN; sh_g = 0; sh_cnt = 0; }

  // vectorized su preload
  {
    uint4* su4 = (uint4*)su;
    const uint4* sg4 = (const uint4*)(sug + (size_t)b * NA);
    for (int v = tid; v < NA / 4; v += 1024) su4[v] = sg4[v];
  }

  // ---- phase 0: scan global 4096-bin h12 -> 12-bit prefix B12 + k ----
  const int* hb = h12g + b * 4096;
  {
    int4 v = ((const int4*)hb)[tid];
    int ssum = v.x + v.y + v.z + v.w;
    int incl = ssum;
    for (int off = 1; off < 64; off <<= 1) {
      int t = __shfl_up(incl, off, 64);
      if (lane >= off) incl += t;
    }
    if (lane == 63) wtot[wv] = incl;
    __syncthreads();
    if (tid < 16) {
      int w0 = wtot[tid];
      int inc2 = w0;
      for (int off = 1; off < 16; off <<= 1) {
        int t = __shfl_up(inc2, off, 16);
        if (tid >= off) inc2 += t;
      }
      wtot[tid] = inc2 - w0;  // exclusive wave base
    }
    __syncthreads();
    int ebase = wtot[wv] + incl - ssum;
    if (ebase < CANDN && ebase + ssum >= CANDN) {  // exactly one thread
      int c = ebase;
      int hh[4] = {v.x, v.y, v.z, v.w};
#pragma unroll
      for (int t = 0; t < 4; ++t) {
        if (c + hh[t] >= CANDN) { sh_pref = (unsigned)(tid * 4 + t); sh_k = CANDN - c; break; }
        c += hh[t];
      }
    }
  }
  __syncthreads();
  unsigned B12 = sh_pref;
  int k = sh_k;

  // ---- pass A: bits [19:12] among (u>>20)==B12, wave-deduped ----
  if (tid < 256) histL[tid] = 0;
  __syncthreads();
  for (int i = tid; i < NA_PAD; i += 1024) {
    bool act = false;
    int d = 0;
    if (i < NA) {
      unsigned u = su[i];
      act = (u >> 20) == B12;
      d = (int)((u >> 12) & 255);
    }
    u64 m = __ballot(act);
    if (m) {
#pragma unroll
      for (int bit = 0; bit < 8; ++bit) {
        u64 bb = __ballot((d >> bit) & 1);
        m &= ((d >> bit) & 1) ? bb : ~bb;
      }
      if (act && (m & ((1ULL << lane) - 1)) == 0ULL)
        atomicAdd(&histL[d], (int)__popcll(m));
    }
  }
  __syncthreads();
  if (tid < 64) {  // inclusive scan of 256 bins
    int v0 = histL[tid * 4 + 0], v1 = histL[tid * 4 + 1];
    int v2 = histL[tid * 4 + 2], v3 = histL[tid * 4 + 3];
    int s0 = v0, s1 = s0 + v1, s2 = s1 + v2, s3 = s2 + v3;
    int tot = s3;
    for (int off = 1; off < 64; off <<= 1) {
      int t = __shfl_up(tot, off, 64);
      if (tid >= off) tot += t;
    }
    int base = tot - s3;
    cum[tid * 4 + 0] = base + s0;
    cum[tid * 4 + 1] = base + s1;
    cum[tid * 4 + 2] = base + s2;
    cum[tid * 4 + 3] = base + s3;
  }
  __syncthreads();
  if (tid < 256) {
    int c = cum[tid];
    int cprev = (tid == 0) ? 0 : cum[tid - 1];
    if (c >= k && cprev < k) {
      sh_pref = (B12 << 8) | (unsigned)tid;  // 20-bit prefix
      sh_k = k - cprev;
    }
  }
  __syncthreads();
  unsigned B20 = sh_pref;
  k = sh_k;

  // ---- pass B: 4096-bin hist of bits [11:0] among (u>>12)==B20 ----
  for (int i = tid; i < 4096; i += 1024) histL[i] = 0;
  __syncthreads();
  for (int i = tid; i < NA; i += 1024) {
    unsigned u = su[i];
    if ((u >> 12) == B20) atomicAdd(&histL[u & 4095], 1);  // sparse: ~tens match
  }
  __syncthreads();
  {
    int bbase = tid * 4;
    int h0 = histL[bbase + 0], h1 = histL[bbase + 1];
    int h2 = histL[bbase + 2], h3 = histL[bbase + 3];
    int ssum = h0 + h1 + h2 + h3;
    int incl = ssum;
    for (int off = 1; off < 64; off <<= 1) {
      int t = __shfl_up(incl, off, 64);
      if (lane >= off) incl += t;
    }
    if (lane == 63) wtot[wv] = incl;
    __syncthreads();
    if (tid < 16) {
      int w0 = wtot[tid];
      int inc2 = w0;
      for (int off = 1; off < 16; off <<= 1) {
        int t = __shfl_up(inc2, off, 16);
        if (tid >= off) inc2 += t;
      }
      wtot[tid] = inc2 - w0;
    }
    __syncthreads();
    int ebase = wtot[wv] + incl - ssum;
    if (ebase < k && ebase + ssum >= k) {  // exactly one thread
      int c = ebase;
      int hh[4] = {h0, h1, h2, h3};
#pragma unroll
      for (int t = 0; t < 4; ++t) {
        if (c + hh[t] >= k) {
          sh_pref = (B20 << 12) | (unsigned)(bbase + t);
          sh_k = k - c;
          break;
        }
        c += hh[t];
      }
    }
  }
  __syncthreads();
  unsigned ustar = sh_pref;
  int kp = sh_k;

  // ---- boundary tie-fix (rank by index) + compaction to global (unsorted) ----
  for (int i = tid; i < NA; i += 1024) {
    if (su[i] == ustar) {
      int p = atomicAdd(&sh_g, 1);
      if (p < 1024) tielist[p] = i;
    }
  }
  __syncthreads();
  int g = sh_g < 1024 ? sh_g : 1024;

  for (int i = tid; i < NA_PAD; i += 1024) {
    bool act = false;
    u64 key = 0;
    if (i < NA) {
      unsigned u = su[i];
      if (u < ustar) act = true;
      else if (u == ustar) {
        int r = 0;
        for (int t2 = 0; t2 < g; ++t2) r += (tielist[t2] < i);
        act = (r < kp);
      }
      key = (((u64)u) << 32) | (unsigned)i;
    }
    u64 mm = __ballot(act);
    if (mm) {
      int leader = __ffsll(mm) - 1;
      int base = 0;
      if (lane == leader) base = atomicAdd(&sh_cnt, (int)__popcll(mm));
      base = __shfl(base, leader, 64);
      if (act)
        keybuf[(size_t)b * CANDN + base + (int)__popcll(mm & ((1ULL << lane) - 1))] = key;
    }
  }
}

// ---------- kernel 3: full-GPU prep gather (slot order) ----------
__global__ __launch_bounds__(256) void prep_kernel(const u64* __restrict__ keybuf,
                                                   const int* __restrict__ clsg,
                                                   const float4* __restrict__ boxTg,
                                                   const int* __restrict__ imgsz,
                                                   float4* __restrict__ nmsbG,
                                                   float* __restrict__ areaG) {
  int s = blockIdx.x * 256 + threadIdx.x;
  int b = blockIdx.y;
  int o = b * CANDN + s;
  u64 key = keybuf[o];
  int idx = (int)(unsigned)(key & 0xFFFFFFFFu);
  float4 bx = boxTg[(size_t)b * NA + idx];
  float inv = (float)(1.0 / (double)imgsz[0]);
  float hw = __fmul_rn(bx.z, 0.5f);
  float hh = __fmul_rn(bx.w, 0.5f);
  float x1 = __fsub_rn(bx.x, hw);
  float y1 = __fsub_rn(bx.y, hh);
  float x2 = __fadd_rn(bx.x, hw);
  float y2 = __fadd_rn(bx.y, hh);
  float clsf = (float)clsg[(size_t)b * NA + idx];
  float nx1 = __fadd_rn(__fmul_rn(x1, inv), clsf);
  float ny1 = __fadd_rn(__fmul_rn(y1, inv), clsf);
  float nx2 = __fadd_rn(__fmul_rn(x2, inv), clsf);
  float ny2 = __fadd_rn(__fmul_rn(y2, inv), clsf);
  float ar = __fmul_rn(__fsub_rn(nx2, nx1), __fsub_rn(ny2, ny1));
  nmsbG[o] = make_float4(nx1, ny1, nx2, ny2);
  areaG[o] = ar;
}

// ---------- kernel 4: sort + chunked fixpoint NMS + output ----------
__global__ __launch_bounds__(1024) void nms_kernel(const u64* __restrict__ keybuf,
                                                   const float4* __restrict__ nmsbG,
                                                   const float* __restrict__ areaG,
                                                   const int* __restrict__ clsg,
                                                   const float4* __restrict__ boxTg,
                                                   float* __restrict__ out) {
  __shared__ alignas(16) u64 skey[CANDN];        // 16384
  __shared__ alignas(16) float4 nmsb[CANDN];     // 32768
  __shared__ float areaA[CANDN];                 // 8192
  __shared__ unsigned short a2s[NA];             // 16800
  __shared__ float4 chunkbox[64];
  __shared__ float chunkarea[64];
  __shared__ float4 keptbox[MAXDET];
  __shared__ float keptarea[MAXDET];
  __shared__ int idxbuf[MAXDET];
  __shared__ u64 diag[64];
  __shared__ u64 supm[16];
  __shared__ int sh_nms;

  int b = blockIdx.x;
  int tid = threadIdx.x;
  int lane = tid & 63;
  int wv = tid >> 6;

  if (tid == 0) sh_nms = 0;

  // load slot-ordered data + build anchor->slot table
  for (int s = tid; s < CANDN; s += 1024) {
    u64 key = keybuf[(size_t)b * CANDN + s];
    skey[s] = key;
    nmsb[s] = nmsbG[(size_t)b * CANDN + s];
    areaA[s] = areaG[(size_t)b * CANDN + s];
    a2s[(unsigned)(key & 0xFFFFFFFFu)] = (unsigned short)s;
  }
  __syncthreads();

  // hybrid bitonic sort: wave w owns slots 128w+l (e0) and 128w+64+l (e1);
  // j<64 via shfl (no barrier), j==64 register pair, j>=128 via LDS.
  int s0 = (wv << 7) + lane;
  int s1 = s0 + 64;
  u64 e0 = skey[s0];
  u64 e1 = skey[s1];
  for (int kk = 2; kk <= CANDN; kk <<= 1) {
    for (int j = kk >> 1; j > 0; j >>= 1) {
      if (j >= 128) {
        skey[s0] = e0;
        skey[s1] = e1;
        __syncthreads();
        u64 p0 = skey[s0 ^ j];
        u64 p1 = skey[s1 ^ j];
        e0 = cswap(e0, p0, s0, j, kk);
        e1 = cswap(e1, p1, s1, j, kk);
        __syncthreads();
      } else if (j == 64) {
        bool asc = (s0 & kk) == 0;
        u64 mn = (e0 < e1) ? e0 : e1;
        u64 mx = (e0 < e1) ? e1 : e0;
        e0 = asc ? mn : mx;
        e1 = asc ? mx : mn;
      } else {
        u64 p0 = shflx64(e0, j);
        u64 p1 = shflx64(e1, j);
        e0 = cswap(e0, p0, s0, j, kk);
        e1 = cswap(e1, p1, s1, j, kk);
      }
    }
  }
  skey[s0] = e0;
  skey[s1] = e1;
  __syncthreads();

  // chunked NMS (chunk=64): cross-chunk vs dense kept list; in-chunk greedy
  // via ballot FIXPOINT (unique fixpoint == greedy by index induction).
#pragma unroll 1
  for (int c = 0; c < 32; ++c) {
    __syncthreads();                 // kept list / sh_nms from prev chunk visible
    int nk0 = sh_nms;
    if (nk0 >= MAXDET) break;        // uniform
    int rank = (c << 6) + lane;
    u64 mykey = skey[rank];
    int slot = a2s[(unsigned)(mykey & 0xFFFFFFFFu)];
    float4 br = nmsb[slot];
    float arr = areaA[slot];
    if (wv == 0) { chunkbox[lane] = br; chunkarea[lane] = arr; }
    bool myvalid = __uint_as_float(~(unsigned)(mykey >> 32)) > 0.25f;
    // cross-chunk: row vs dense kept list, strided over 16 waves
    bool sup = false;
    for (int q = wv; q < nk0; q += 16)
      sup = sup || iou_gt(br, arr, keptbox[q], keptarea[q]);
    u64 sm = __ballot(sup);
    if (lane == 0) supm[wv] = sm;
    __syncthreads();                 // chunkbox ready
    // in-chunk diag: wave wv computes rows 4wv..4wv+3 vs all 64 lanes
#pragma unroll
    for (int rr = 0; rr < 4; ++rr) {
      int r = (wv << 2) + rr;
      bool supd = iou_gt(chunkbox[r], chunkarea[r], br, arr);
      u64 bb = __ballot(supd);
      if (lane == 0) diag[r] = bb;
    }
    u64 vb = __ballot(myvalid);      // wave0's lanes = chunk rows 0..63
    __syncthreads();                 // supm/diag ready
    if (wv == 0) {                   // wave 0 resolves chunk c via fixpoint
      u64 orsup = 0ULL;
#pragma unroll
      for (int w = 0; w < 16; ++w) orsup |= supm[w];
      bool tent = (((vb >> lane) & 1ULL) != 0ULL) &&
                  (((orsup >> lane) & 1ULL) == 0ULL);
      u64 below = (lane == 0) ? 0ULL : ((1ULL << lane) - 1ULL);
      u64 colbelow = diag[lane] & below;  // lower-indexed suppressors of me
      u64 kept = __ballot(tent);
      for (int it = 0; it < 64; ++it) {
        bool alive = tent && ((kept & colbelow) == 0ULL);
        u64 nk = __ballot(alive);
        if (nk == kept) break;       // fixpoint (unique) == greedy result
        kept = nk;
      }
      int nadd = (int)__popcll(kept);
      int cnt = nk0 + nadd;
      if (cnt > MAXDET) cnt = MAXDET;
      bool mine = ((kept >> lane) & 1ULL) != 0ULL;
      int pos = nk0 + (int)__popcll(kept & below);
      if (mine && pos < MAXDET) {
        idxbuf[pos] = rank;
        keptbox[pos] = br;
        keptarea[pos] = arr;
      }
      if (lane == 0) sh_nms = cnt;
    }
  }
  __syncthreads();

  // output (re-gather, identical rounding ops -> bit-exact)
  int total = sh_nms;
  if (tid < MAXDET) {
    float vals[6] = {0.f, 0.f, 0.f, 0.f, 0.f, 0.f};
    if (tid < total) {
      int rank = idxbuf[tid];
      u64 key = skey[rank];
      int idx = (int)(unsigned)(key & 0xFFFFFFFFu);
      float score = __uint_as_float(~(unsigned)(key >> 32));
      float4 bx = boxTg[(size_t)b * NA + idx];
      float hw = __fmul_rn(bx.z, 0.5f);
      float hh = __fmul_rn(bx.w, 0.5f);
      vals[0] = __fsub_rn(bx.x, hw);
      vals[1] = __fsub_rn(bx.y, hh);
      vals[2] = __fadd_rn(bx.x, hw);
      vals[3] = __fadd_rn(bx.y, hh);
      vals[4] = score;
      vals[5] = (float)clsg[(size_t)b * NA + idx];
    }
#pragma unroll
    for (int q = 0; q < 6; ++q)
      out[((size_t)(b * MAXDET) + tid) * 6 + q] = vals[q];
  }
}

extern "C" void kernel_launch(void* const* d_in, const int* in_sizes, int n_in,
                              void* d_out, int out_size, void* d_ws, size_t ws_size,
                              hipStream_t stream) {
  (void)in_sizes; (void)n_in; (void)out_size; (void)ws_size;
  const float* pred = (const float*)d_in[0];
  const int* imgsz = (const int*)d_in[1];
  char* ws = (char*)d_ws;
  unsigned* sug = (unsigned*)(ws + OFF_SU);
  int* cls = (int*)(ws + OFF_CLS);
  float4* boxT = (float4*)(ws + OFF_BOX);
  u64* keybuf = (u64*)(ws + OFF_KEY);
  float4* nmsbG = (float4*)(ws + OFF_NMSB);
  float* areaG = (float*)(ws + OFF_AREA);
  int* h12 = (int*)(ws + OFF_H12);
  float* out = (float*)d_out;

  zero_kernel<<<256, 256, 0, stream>>>(h12);
  score_kernel<<<dim3((NA + 255) / 256, NB), 256, 0, stream>>>(pred, sug, cls, boxT,
                                                               h12);
  select_kernel<<<NB, 1024, 0, stream>>>(sug, h12, keybuf);
  prep_kernel<<<dim3(CANDN / 256, NB), 256, 0, stream>>>(keybuf, cls, boxT, imgsz,
                                                         nmsbG, areaG);
  nms_kernel<<<NB, 1024, 0, stream>>>(keybuf, nmsbG, areaG, cls, boxT, out);
}

// Round 15
// 66.806 us; speedup vs baseline: 1.0871x; 1.0871x over previous
//
#include <hip/hip_runtime.h>
#include <stdint.h>

#define NB 16
#define NA 8400
#define NA_PAD 9216
#define NCH 84
#define NCLS 80
#define CANDN 2048
#define MAXDET 300

typedef unsigned long long u64;

// ---------------- workspace layout (bytes) ----------------
static const size_t OFF_SU   = 0;         // 16*8400*4  = 537600
static const size_t OFF_CLS  = 537600;    // 16*8400*4  = 537600
static const size_t OFF_BOX  = 1075200;   // 16*8400*16 = 2150400
static const size_t OFF_KEY  = 3225600;   // 16*2048*8  = 262144
static const size_t OFF_NMSB = 3487744;   // 16*2048*16 = 524288
static const size_t OFF_AREA = 4012032;   // 16*2048*4  = 131072
static const size_t OFF_H12  = 4143104;   // 16*4096*4  = 262144
static const size_t OFF_H16  = 4405248;   // 16*65536*4 = 4194304
static const size_t OFF_CLSB = 8599552;   // 16*2048*1  = 32768
// total ~8.7 MB

// ---------- kernel 0: zero h12+h16 (4.4 MB, contiguous) at full BW ----------
__global__ __launch_bounds__(256) void zero_kernel(int* __restrict__ h) {
  h[blockIdx.x * 256 + threadIdx.x] = 0;  // grid sized exactly
}

// ---------- kernel 1: score/argmax + boxT + deduped global histograms ----------
__global__ __launch_bounds__(256) void score_kernel(const float* __restrict__ pred,
                                                    unsigned* __restrict__ sug,
                                                    int* __restrict__ cls,
                                                    float4* __restrict__ boxT,
                                                    int* __restrict__ h12,
                                                    int* __restrict__ h16) {
  int a = blockIdx.x * 256 + threadIdx.x;
  int b = blockIdx.y;
  if (a >= NA) return;
  int lane = threadIdx.x & 63;
  const float* pbase = pred + (size_t)b * (NCH * NA);
  const float* p = pbase + 4 * NA + a;
  float best = p[0];
  int bc = 0;
#pragma unroll 8
  for (int c = 1; c < NCLS; ++c) {
    float v = p[(size_t)c * NA];
    if (v > best) { best = v; bc = c; }  // strict > : first-index argmax
  }
  unsigned u = ~__float_as_uint(best);  // ascending u == descending score
  sug[(size_t)b * NA + a] = u;
  cls[(size_t)b * NA + a] = bc;
  boxT[(size_t)b * NA + a] =
      make_float4(pbase[a], pbase[NA + a], pbase[2 * NA + a], pbase[3 * NA + a]);
  // wave-deduped histogram atomics (scores cluster -> same-bin storms otherwise)
  u64 m = __ballot(true);
  u64 m12 = 0;
#pragma unroll
  for (int bit = 31; bit >= 16; --bit) {
    u64 bb = __ballot((u >> bit) & 1);
    m &= ((u >> bit) & 1) ? bb : ~bb;
    if (bit == 20) m12 = m;
  }
  u64 below = (lane == 0) ? 0ULL : ((1ULL << lane) - 1ULL);
  if ((m12 & below) == 0ULL)
    atomicAdd(&h12[b * 4096 + (int)(u >> 20)], (int)__popcll(m12));
  if ((m & below) == 0ULL)
    atomicAdd(&h16[b * 65536 + (int)(u >> 16)], (int)__popcll(m));
}

__device__ inline u64 shflx64(u64 v, int m) {
  int lo = __shfl_xor((int)(unsigned)(v & 0xFFFFFFFFu), m, 64);
  int hi = __shfl_xor((int)(unsigned)(v >> 32), m, 64);
  return (((u64)(unsigned)hi) << 32) | (unsigned)lo;
}

__device__ inline u64 cswap(u64 a, u64 b, int s, int j, int kk) {
  bool low = (s & j) == 0;
  bool asc = (s & kk) == 0;
  bool takeMin = (low == asc);
  u64 mn = (a < b) ? a : b;
  u64 mx = (a < b) ? b : a;
  return takeMin ? mn : mx;
}

// exact division-free IoU>0.45f compare (25x24-bit f64 product is exact)
__device__ inline bool iou_gt(float4 bi, float ai, float4 bj, float aj) {
  const double THR = 0x1.CCCCCC8p-2;  // 0.45f + 2^-26 exactly
  float ix1 = fmaxf(bi.x, bj.x);
  float iy1 = fmaxf(bi.y, bj.y);
  float ix2 = fminf(bi.z, bj.z);
  float iy2 = fminf(bi.w, bj.w);
  float iw = fmaxf(__fsub_rn(ix2, ix1), 0.0f);
  float ih = fmaxf(__fsub_rn(iy2, iy1), 0.0f);
  float inter = __fmul_rn(iw, ih);
  float den = __fadd_rn(__fsub_rn(__fadd_rn(ai, aj), inter), 1e-7f);
  return (double)inter > THR * (double)den;
}

// ---------- kernel 2: histogram-guided select (R13 form) ----------
__global__ __launch_bounds__(1024) void select_kernel(const unsigned* __restrict__ sug,
                                                      const int* __restrict__ h12g,
                                                      const int* __restrict__ h16g,
                                                      u64* __restrict__ keybuf) {
  __shared__ alignas(16) unsigned su[NA];  // 33600 B
  __shared__ int hist8[256];
  __shared__ int cum[256];
  __shared__ int tielist[1024];
  __shared__ int sl16[16];
  __shared__ int wtot[16];
  __shared__ unsigned sh_pref;
  __shared__ int sh_k, sh_g, sh_cnt;

  int b = blockIdx.x;
  int tid = threadIdx.x;
  int lane = tid & 63;
  int wv = tid >> 6;

  if (tid == 0) { sh_pref = 0; sh_k = CANDN; sh_g = 0; sh_cnt = 0; }

  // vectorized su preload
  {
    uint4* su4 = (uint4*)su;
    const uint4* sg4 = (const uint4*)(sug + (size_t)b * NA);
    for (int v = tid; v < NA / 4; v += 1024) su4[v] = sg4[v];
  }

  // ---- phase 0: scan global 4096-bin h12 -> 12-bit prefix + k ----
  const int* hb = h12g + b * 4096;
  int4 v = ((const int4*)hb)[tid];
  int ssum = v.x + v.y + v.z + v.w;
  int incl = ssum;
  for (int off = 1; off < 64; off <<= 1) {
    int t = __shfl_up(incl, off, 64);
    if (lane >= off) incl += t;
  }
  if (lane == 63) wtot[wv] = incl;
  __syncthreads();
  if (tid < 16) {
    int w0 = wtot[tid];
    int inc2 = w0;
    for (int off = 1; off < 16; off <<= 1) {
      int t = __shfl_up(inc2, off, 16);
      if (tid >= off) inc2 += t;
    }
    wtot[tid] = inc2 - w0;  // exclusive wave base
  }
  __syncthreads();
  int ebase = wtot[wv] + incl - ssum;
  if (ebase < CANDN && ebase + ssum >= CANDN) {  // exactly one thread
    int c = ebase;
    int hh[4] = {v.x, v.y, v.z, v.w};
#pragma unroll
    for (int t = 0; t < 4; ++t) {
      if (c + hh[t] >= CANDN) { sh_pref = (unsigned)(tid * 4 + t); sh_k = CANDN - c; break; }
      c += hh[t];
    }
  }
  __syncthreads();
  unsigned B12 = sh_pref;
  int k = sh_k;

  // ---- phase 0b: 16-bin h16 slice -> 16-bit prefix + k ----
  if (tid < 16) sl16[tid] = h16g[(size_t)b * 65536 + B12 * 16 + tid];
  __syncthreads();
  if (tid == 0) {
    int c = 0;
#pragma unroll
    for (int j = 0; j < 16; ++j) {
      int h = sl16[j];
      if (c + h >= k) { sh_pref = (B12 << 4) + (unsigned)j; sh_k = k - c; break; }
      c += h;
    }
  }
  __syncthreads();
  unsigned B16 = sh_pref;
  k = sh_k;

  // ---- pass A: bits [15:8] among (u>>16)==B16 (sparse) ----
  if (tid < 256) hist8[tid] = 0;
  __syncthreads();
  for (int i = tid; i < NA; i += 1024) {
    unsigned u = su[i];
    if ((u >> 16) == B16) atomicAdd(&hist8[(u >> 8) & 255], 1);
  }
  __syncthreads();
  if (tid < 64) {  // inclusive scan of 256 bins
    int v0 = hist8[tid * 4 + 0], v1 = hist8[tid * 4 + 1];
    int v2 = hist8[tid * 4 + 2], v3 = hist8[tid * 4 + 3];
    int s0 = v0, s1 = s0 + v1, s2 = s1 + v2, s3 = s2 + v3;
    int tot = s3;
    for (int off = 1; off < 64; off <<= 1) {
      int t = __shfl_up(tot, off, 64);
      if (tid >= off) tot += t;
    }
    int base = tot - s3;
    cum[tid * 4 + 0] = base + s0;
    cum[tid * 4 + 1] = base + s1;
    cum[tid * 4 + 2] = base + s2;
    cum[tid * 4 + 3] = base + s3;
  }
  __syncthreads();
  if (tid < 256) {
    int c = cum[tid];
    int cprev = (tid == 0) ? 0 : cum[tid - 1];
    if (c >= k && cprev < k) {
      sh_pref = (B16 << 16) | ((unsigned)tid << 8);
      sh_k = k - cprev;
    }
  }
  __syncthreads();
  unsigned p24 = sh_pref;
  k = sh_k;

  // ---- pass B: bits [7:0] among (u & 0xFFFFFF00)==p24 ----
  if (tid < 256) hist8[tid] = 0;
  __syncthreads();
  for (int i = tid; i < NA; i += 1024) {
    unsigned u = su[i];
    if ((u & 0xFFFFFF00u) == p24) atomicAdd(&hist8[u & 255], 1);
  }
  __syncthreads();
  if (tid < 64) {
    int v0 = hist8[tid * 4 + 0], v1 = hist8[tid * 4 + 1];
    int v2 = hist8[tid * 4 + 2], v3 = hist8[tid * 4 + 3];
    int s0 = v0, s1 = s0 + v1, s2 = s1 + v2, s3 = s2 + v3;
    int tot = s3;
    for (int off = 1; off < 64; off <<= 1) {
      int t = __shfl_up(tot, off, 64);
      if (tid >= off) tot += t;
    }
    int base = tot - s3;
    cum[tid * 4 + 0] = base + s0;
    cum[tid * 4 + 1] = base + s1;
    cum[tid * 4 + 2] = base + s2;
    cum[tid * 4 + 3] = base + s3;
  }
  __syncthreads();
  if (tid < 256) {
    int c = cum[tid];
    int cprev = (tid == 0) ? 0 : cum[tid - 1];
    if (c >= k && cprev < k) {
      sh_pref = p24 | (unsigned)tid;
      sh_k = k - cprev;
    }
  }
  __syncthreads();
  unsigned ustar = sh_pref;
  int kp = sh_k;

  // ---- boundary tie-fix (rank by index) + compaction to global (unsorted) ----
  for (int i = tid; i < NA; i += 1024) {
    if (su[i] == ustar) {
      int p = atomicAdd(&sh_g, 1);
      if (p < 1024) tielist[p] = i;
    }
  }
  __syncthreads();
  int g = sh_g < 1024 ? sh_g : 1024;

  for (int i = tid; i < NA_PAD; i += 1024) {
    bool act = false;
    u64 key = 0;
    if (i < NA) {
      unsigned u = su[i];
      if (u < ustar) act = true;
      else if (u == ustar) {
        int r = 0;
        for (int t2 = 0; t2 < g; ++t2) r += (tielist[t2] < i);
        act = (r < kp);
      }
      key = (((u64)u) << 32) | (unsigned)i;
    }
    u64 mm = __ballot(act);
    if (mm) {
      int leader = __ffsll(mm) - 1;
      int base = 0;
      if (lane == leader) base = atomicAdd(&sh_cnt, (int)__popcll(mm));
      base = __shfl(base, leader, 64);
      if (act)
        keybuf[(size_t)b * CANDN + base + (int)__popcll(mm & ((1ULL << lane) - 1))] = key;
    }
  }
}

// ---------- kernel 3: full-GPU prep gather (slot order) ----------
__global__ __launch_bounds__(256) void prep_kernel(const u64* __restrict__ keybuf,
                                                   const int* __restrict__ clsg,
                                                   const float4* __restrict__ boxTg,
                                                   const int* __restrict__ imgsz,
                                                   float4* __restrict__ nmsbG,
                                                   float* __restrict__ areaG,
                                                   unsigned char* __restrict__ clsbG) {
  int s = blockIdx.x * 256 + threadIdx.x;
  int b = blockIdx.y;
  int o = b * CANDN + s;
  u64 key = keybuf[o];
  int idx = (int)(unsigned)(key & 0xFFFFFFFFu);
  float4 bx = boxTg[(size_t)b * NA + idx];
  float inv = (float)(1.0 / (double)imgsz[0]);
  float hw = __fmul_rn(bx.z, 0.5f);
  float hh = __fmul_rn(bx.w, 0.5f);
  float x1 = __fsub_rn(bx.x, hw);
  float y1 = __fsub_rn(bx.y, hh);
  float x2 = __fadd_rn(bx.x, hw);
  float y2 = __fadd_rn(bx.y, hh);
  int ci = clsg[(size_t)b * NA + idx];
  float clsf = (float)ci;
  float nx1 = __fadd_rn(__fmul_rn(x1, inv), clsf);
  float ny1 = __fadd_rn(__fmul_rn(y1, inv), clsf);
  float nx2 = __fadd_rn(__fmul_rn(x2, inv), clsf);
  float ny2 = __fadd_rn(__fmul_rn(y2, inv), clsf);
  float ar = __fmul_rn(__fsub_rn(nx2, nx1), __fsub_rn(ny2, ny1));
  nmsbG[o] = make_float4(nx1, ny1, nx2, ny2);
  areaG[o] = ar;
  clsbG[o] = (unsigned char)ci;
}

// ---------- kernel 4: sort + chunked NMS (class-bucketed kept list) ----------
__global__ __launch_bounds__(1024) void nms_kernel(const u64* __restrict__ keybuf,
                                                   const float4* __restrict__ nmsbG,
                                                   const float* __restrict__ areaG,
                                                   const unsigned char* __restrict__ clsbG,
                                                   const int* __restrict__ clsg,
                                                   const float4* __restrict__ boxTg,
                                                   float* __restrict__ out) {
  __shared__ alignas(16) u64 skey[CANDN];        // 16384
  __shared__ alignas(16) float4 nmsb[CANDN];     // 32768
  __shared__ float areaA[CANDN];                 // 8192
  __shared__ unsigned short a2s[NA];             // 16800
  __shared__ unsigned char clsA[CANDN];          // 2048
  __shared__ float4 chunkbox[64];
  __shared__ float chunkarea[64];
  // class buckets for kept boxes: |class diff|>=2 has exactly zero IoU
  __shared__ float4 bbox[NCLS][16];              // 20480
  __shared__ float barea[NCLS][16];              // 5120
  __shared__ int bcount[NCLS];                   // 320
  __shared__ float4 ovfbox[MAXDET];              // 4800 (exact overflow path)
  __shared__ float ovfarea[MAXDET];              // 1200
  __shared__ int idxbuf[MAXDET];                 // 1200
  __shared__ u64 diag[64];
  __shared__ u64 supx[4];
  __shared__ u64 vmaskc;
  __shared__ int sh_nms, sh_ovf;

  int b = blockIdx.x;
  int tid = threadIdx.x;
  int lane = tid & 63;
  int wv = tid >> 6;

  if (tid == 0) { sh_nms = 0; sh_ovf = 0; }
  if (tid < NCLS) bcount[tid] = 0;

  // load slot-ordered data + build anchor->slot table
  for (int s = tid; s < CANDN; s += 1024) {
    u64 key = keybuf[(size_t)b * CANDN + s];
    skey[s] = key;
    nmsb[s] = nmsbG[(size_t)b * CANDN + s];
    areaA[s] = areaG[(size_t)b * CANDN + s];
    clsA[s] = clsbG[(size_t)b * CANDN + s];
    a2s[(unsigned)(key & 0xFFFFFFFFu)] = (unsigned short)s;
  }
  __syncthreads();

  // hybrid bitonic sort: wave w owns slots 128w+l (e0) and 128w+64+l (e1)
  int s0 = (wv << 7) + lane;
  int s1 = s0 + 64;
  u64 e0 = skey[s0];
  u64 e1 = skey[s1];
  for (int kk = 2; kk <= CANDN; kk <<= 1) {
    for (int j = kk >> 1; j > 0; j >>= 1) {
      if (j >= 128) {
        skey[s0] = e0;
        skey[s1] = e1;
        __syncthreads();
        u64 p0 = skey[s0 ^ j];
        u64 p1 = skey[s1 ^ j];
        e0 = cswap(e0, p0, s0, j, kk);
        e1 = cswap(e1, p1, s1, j, kk);
        __syncthreads();
      } else if (j == 64) {
        bool asc = (s0 & kk) == 0;
        u64 mn = (e0 < e1) ? e0 : e1;
        u64 mx = (e0 < e1) ? e1 : e0;
        e0 = asc ? mn : mx;
        e1 = asc ? mx : mn;
      } else {
        u64 p0 = shflx64(e0, j);
        u64 p1 = shflx64(e1, j);
        e0 = cswap(e0, p0, s0, j, kk);
        e1 = cswap(e1, p1, s1, j, kk);
      }
    }
  }
  skey[s0] = e0;
  skey[s1] = e1;
  __syncthreads();

  // chunked NMS (chunk=64): cross-chunk via class buckets; tent-gated diag;
  // wave-0 ballot fixpoint (unique fixpoint == greedy by index induction).
#pragma unroll 1
  for (int c = 0; c < 32; ++c) {
    __syncthreads();                 // bucket appends / sh_nms visible
    int nk0 = sh_nms;
    if (nk0 >= MAXDET) break;        // uniform
    int rank = (c << 6) + lane;
    u64 mykey = skey[rank];
    int slot = a2s[(unsigned)(mykey & 0xFFFFFFFFu)];
    float4 br = nmsb[slot];
    float arr = areaA[slot];
    int myc = clsA[slot];
    if (wv == 0) {
      chunkbox[lane] = br;
      chunkarea[lane] = arr;
      u64 vb = __ballot(__uint_as_float(~(unsigned)(mykey >> 32)) > 0.25f);
      if (lane == 0) vmaskc = vb;
    }
    // cross-chunk: waves 0..2 check bucket (myc-1+wv), wave 3 checks overflow
    if (wv < 3) {
      int cc = myc - 1 + wv;
      bool ok = (cc >= 0 && cc < NCLS);
      int n = ok ? bcount[cc] : 0;
      bool sup = false;
      for (int q = 0; q < n; ++q)
        sup = sup || iou_gt(br, arr, bbox[cc][q], barea[cc][q]);
      u64 sm = __ballot(sup);
      if (lane == 0) supx[wv] = sm;
    } else if (wv == 3) {
      int n = sh_ovf;
      bool sup = false;
      for (int q = 0; q < n; ++q)
        sup = sup || iou_gt(br, arr, ovfbox[q], ovfarea[q]);
      u64 sm = __ballot(sup);
      if (lane == 0) supx[3] = sm;
    }
    __syncthreads();                 // supx/chunkbox/vmaskc ready
    u64 tentg = vmaskc & ~(supx[0] | supx[1] | supx[2] | supx[3]);
    // tent-gated in-chunk diag: only tentative rows can be kept/suppress
#pragma unroll
    for (int rr = 0; rr < 4; ++rr) {
      int r = (wv << 2) + rr;
      if ((tentg >> r) & 1ULL) {
        bool supd = iou_gt(chunkbox[r], chunkarea[r], br, arr);
        u64 bb = __ballot(supd);
        if (lane == 0) diag[r] = bb;
      } else if (lane == 0) {
        diag[r] = 0ULL;
      }
    }
    __syncthreads();                 // diag ready
    if (wv == 0) {                   // wave 0 resolves chunk c via fixpoint
      bool tent = ((tentg >> lane) & 1ULL) != 0ULL;
      u64 below = (lane == 0) ? 0ULL : ((1ULL << lane) - 1ULL);
      u64 colbelow = diag[lane] & below;  // lower-indexed suppressors of me
      u64 kept = __ballot(tent);
      for (int it = 0; it < 64; ++it) {
        bool alive = tent && ((kept & colbelow) == 0ULL);
        u64 nk = __ballot(alive);
        if (nk == kept) break;       // unique fixpoint == greedy result
        kept = nk;
      }
      int cnt = nk0 + (int)__popcll(kept);
      if (cnt > MAXDET) cnt = MAXDET;
      bool mine = ((kept >> lane) & 1ULL) != 0ULL;
      int pos = nk0 + (int)__popcll(kept & below);
      if (mine && pos < MAXDET) {
        idxbuf[pos] = rank;
        int n = atomicAdd(&bcount[myc], 1);
        if (n < 16) { bbox[myc][n] = br; barea[myc][n] = arr; }
        else {
          int mo = atomicAdd(&sh_ovf, 1);
          ovfbox[mo] = br;
          ovfarea[mo] = arr;
        }
      }
      if (lane == 0) sh_nms = cnt;
    }
  }
  __syncthreads();

  // output (re-gather, identical rounding ops -> bit-exact)
  int total = sh_nms;
  if (tid < MAXDET) {
    float vals[6] = {0.f, 0.f, 0.f, 0.f, 0.f, 0.f};
    if (tid < total) {
      int rank = idxbuf[tid];
      u64 key = skey[rank];
      int idx = (int)(unsigned)(key & 0xFFFFFFFFu);
      float score = __uint_as_float(~(unsigned)(key >> 32));
      float4 bx = boxTg[(size_t)b * NA + idx];
      float hw = __fmul_rn(bx.z, 0.5f);
      float hh = __fmul_rn(bx.w, 0.5f);
      vals[0] = __fsub_rn(bx.x, hw);
      vals[1] = __fsub_rn(bx.y, hh);
      vals[2] = __fadd_rn(bx.x, hw);
      vals[3] = __fadd_rn(bx.y, hh);
      vals[4] = score;
      vals[5] = (float)clsg[(size_t)b * NA + idx];
    }
#pragma unroll
    for (int q = 0; q < 6; ++q)
      out[((size_t)(b * MAXDET) + tid) * 6 + q] = vals[q];
  }
}

extern "C" void kernel_launch(void* const* d_in, const int* in_sizes, int n_in,
                              void* d_out, int out_size, void* d_ws, size_t ws_size,
                              hipStream_t stream) {
  (void)in_sizes; (void)n_in; (void)out_size; (void)ws_size;
  const float* pred = (const float*)d_in[0];
  const int* imgsz = (const int*)d_in[1];
  char* ws = (char*)d_ws;
  unsigned* sug = (unsigned*)(ws + OFF_SU);
  int* cls = (int*)(ws + OFF_CLS);
  float4* boxT = (float4*)(ws + OFF_BOX);
  u64* keybuf = (u64*)(ws + OFF_KEY);
  float4* nmsbG = (float4*)(ws + OFF_NMSB);
  float* areaG = (float*)(ws + OFF_AREA);
  int* h12 = (int*)(ws + OFF_H12);
  int* h16 = (int*)(ws + OFF_H16);
  unsigned char* clsb = (unsigned char*)(ws + OFF_CLSB);
  float* out = (float*)d_out;

  zero_kernel<<<(262144 + 4194304) / 4 / 256, 256, 0, stream>>>(h12);
  score_kernel<<<dim3((NA + 255) / 256, NB), 256, 0, stream>>>(pred, sug, cls, boxT,
                                                               h12, h16);
  select_kernel<<<NB, 1024, 0, stream>>>(sug, h12, h16, keybuf);
  prep_kernel<<<dim3(CANDN / 256, NB), 256, 0, stream>>>(keybuf, cls, boxT, imgsz,
                                                         nmsbG, areaG, clsb);
  nms_kernel<<<NB, 1024, 0, stream>>>(keybuf, nmsbG, areaG, clsb, cls, boxT, out);
}